// Round 1
// 203.143 us; speedup vs baseline: 1.0706x; 1.0706x over previous
//
#include <hip/hip_runtime.h>
#include <hip/hip_bf16.h>
#include <math.h>

// Problem constants
#define Bn  4
#define Cc  64
#define MHc 18
#define Hh  128
#define Wd  128
#define HW  (Hh*Wd)
#define Np  9
#define HP  130
#define WP  130
#define XPE (HP*WP*Cc)     // xpad elems per batch (bf16): 1,081,600
#define PPE (HP*WP*32)     // popad/ropad elems per batch: 540,800
#define KX  576            // x-tap K (9*64)
#define KP  288            // po-tap K (9*32)
#define KT  (KX+KP)        // 864 total K, 27 MFMA steps

typedef __attribute__((ext_vector_type(8))) short short8;
typedef __attribute__((ext_vector_type(4))) float float4v;

__device__ __forceinline__ float bf2f(__hip_bfloat16 x) { return __bfloat162float(x); }
__device__ __forceinline__ __hip_bfloat16 f2bf(float x) { return __float2bfloat16(x); }
__device__ __forceinline__ float sigm(float x) { return 1.f / (1.f + expf(-x)); }
__device__ __forceinline__ float s2f(short s) {            // bf16 bits -> f32
  return __uint_as_float(((unsigned)(unsigned short)s) << 16);
}
__device__ __forceinline__ short f2bs(float x) {           // f32 -> bf16 bits (RNE)
  __hip_bfloat16 h = __float2bfloat16(x);
  return *reinterpret_cast<short*>(&h);
}

#define NW1 (64*KT)          // 55296
#define NW2 (32*KP)          // 9216
#define NW3 (Cc*Cc*Np)       // 36864  (total 101376 = 396*256)

// ---------------------------------------------------------------------------
// K1: merged prep. (unchanged)
// blk <4096: xpad interior | 4096..4607: popad | 4608..5003: weight packs
// ---------------------------------------------------------------------------
__global__ __launch_bounds__(256)
void k_prep(const float* __restrict__ x, const float* __restrict__ po,
            const float* __restrict__ upd_w, const float* __restrict__ rst_w,
            const float* __restrict__ out_w, const float* __restrict__ wg_w,
            const float* __restrict__ wcw,
            __hip_bfloat16* __restrict__ xp, __hip_bfloat16* __restrict__ pp,
            __hip_bfloat16* __restrict__ wall, __hip_bfloat16* __restrict__ w2,
            __hip_bfloat16* __restrict__ wt) {
  __shared__ float tile[16][65];
  int blk = blockIdx.x;
  int t = threadIdx.x;
  if (blk < 4096) {
    int wtile = blk & 7;
    int h = (blk >> 3) & 127;
    int b = blk >> 10;
    int w0 = wtile * 16;
    int wa = t & 15, cq = t >> 4;
    #pragma unroll
    for (int j = 0; j < 4; ++j) {
      int c = cq * 4 + j;
      tile[wa][c] = x[(b*Cc + c)*HW + h*Wd + w0 + wa];
    }
    __syncthreads();
    int cb = t & 63, wq = t >> 6;
    #pragma unroll
    for (int j = 0; j < 4; ++j) {
      int w = wq * 4 + j;
      xp[b*XPE + ((h+1)*WP + (w0 + w + 1))*Cc + cb] = f2bf(tile[w][cb]);
    }
  } else if (blk < 4608) {
    int pb = blk - 4096;            // b*128 + h
    int h = pb & 127;
    int b = pb >> 7;
    int w = t & 127;
    int half = t >> 7;
    for (int j = 0; j < 9; ++j) {
      int ch = half * 9 + j;
      float v = po[(b*MHc + ch)*HW + h*Wd + w];
      pp[b*PPE + ((h+1)*WP + (w+1))*32 + ch] = f2bf(v);
    }
  } else {
    int idx = (blk - 4608) * 256 + t;
    if (idx < NW1) {
      int k  = idx % KT;
      int gr = idx / KT;
      float v = 0.f;
      if (k < KX) {
        int n = k >> 6, ci = k & 63;
        if      (gr < 18) v = upd_w[(gr*(Cc+MHc) + ci)*9 + n];
        else if (gr < 36) v = rst_w[((gr-18)*(Cc+MHc) + ci)*9 + n];
        else if (gr < 54) v = out_w[((gr-36)*(Cc+MHc) + ci)*9 + n];
        else if (gr < 63) v = wg_w[((gr-54)*Cc + ci)*9 + n];
      } else {
        int kk = k - KX;
        int n = kk >> 5, jc = kk & 31;
        if (jc < 18) {
          if      (gr < 18) v = upd_w[(gr*(Cc+MHc) + Cc + jc)*9 + n];
          else if (gr < 36) v = rst_w[((gr-18)*(Cc+MHc) + Cc + jc)*9 + n];
        }
      }
      wall[idx] = f2bf(v);
    } else if (idx < NW1 + NW2) {
      int i2 = idx - NW1;
      int k  = i2 % KP;
      int oc = i2 / KP;
      int n = k >> 5, jc = k & 31;
      float v = (oc < 18 && jc < 18) ? out_w[(oc*(Cc+MHc) + Cc + jc)*9 + n] : 0.f;
      w2[i2] = f2bf(v);
    } else if (idx < NW1 + NW2 + NW3) {
      int i3 = idx - NW1 - NW2;
      int k  = i3 % 576;
      int co = i3 / 576;
      wt[i3] = f2bf(wcw[(co*Cc + (k & 63))*9 + (k >> 6)]);
    }
  }
}

// ---------------------------------------------------------------------------
// K2: all-gates MFMA GEMM (M=64 x K=864 x 16px/block).
// NEW: no im2col. Stage raw 3x18 window (x:64ch, po:32ch) with 16B vector
// loads + XOR-swizzled LDS writes; MFMA B-fragments read directly from the
// window with compile-time tap addressing (same values as the old sh[] K-
// layout, so the GEMM is bit-identical).
// ---------------------------------------------------------------------------
__global__ __launch_bounds__(256)
void k_gates(const __hip_bfloat16* __restrict__ xpad,
             const __hip_bfloat16* __restrict__ popad,
             const __hip_bfloat16* __restrict__ wall,
             const float* __restrict__ po,
             const float* __restrict__ upd_b,
             const float* __restrict__ rst_b,
             const float* __restrict__ out_b,
             const float* __restrict__ wg_b,
             float* __restrict__ u_out,      // aliases out_mn
             float* __restrict__ cx_out,     // aliases out_off
             __hip_bfloat16* __restrict__ ropad,
             __hip_bfloat16* __restrict__ m_t) {
  // winx: [3][18][64] bf16 = 6912B, rows of 128B, slot-swizzled by (row&7)
  // winp: [3][18][32] bf16 = 3456B, rows of  64B, slot-swizzled by (row&3)
  __shared__ __align__(16) char winx[6912];
  __shared__ __align__(16) char winp[3456];
  __shared__ __align__(16) __hip_bfloat16 roL[16][32];
  int blk = blockIdx.x;
  int wtile = blk & 7;
  int h = (blk >> 3) & 127;
  int b = blk >> 10;
  int w0 = wtile * 16;
  int lane = threadIdx.x & 63;
  int wave = threadIdx.x >> 6;
  int t = threadIdx.x;

  ((unsigned int*)roL)[t] = 0u;      // zero all 512 bf16 (incl. ch 18..31)

  const __hip_bfloat16* xpb = xpad + b * XPE;
  const __hip_bfloat16* ppb = popad + b * PPE;

  // stage x window: 432 x 16B chunks (row = 144 chunks, contiguous in global)
  for (int i = t; i < 432; i += 256) {
    int r = i / 144, cidx = i - r * 144;
    short8 v = *reinterpret_cast<const short8*>(
        xpb + ((h + r) * WP + w0) * Cc + cidx * 8);
    int o = i * 16;
    *reinterpret_cast<short8*>(winx + (o ^ (((o >> 7) & 7) << 4))) = v;
  }
  // stage po window: 216 x 16B chunks (row = 72 chunks)
  if (t < 216) {
    int r = t / 72, cidx = t - r * 72;
    short8 v = *reinterpret_cast<const short8*>(
        ppb + ((h + r) * WP + w0) * 32 + cidx * 8);
    int o = t * 16;
    *reinterpret_cast<short8*>(winp + (o ^ (((o >> 6) & 3) << 4))) = v;
  }
  __syncthreads();

  int mrow = lane & 15;
  int quad = lane >> 4;
  int cotile = wave * 16;
  float4v acc = {0.f, 0.f, 0.f, 0.f};
  #pragma unroll
  for (int ks = 0; ks < KT/32; ++ks) {
    short8 a = *reinterpret_cast<const short8*>(
        wall + (cotile + mrow) * KT + ks * 32 + quad * 8);
    short8 bfr;
    if (ks < 18) {
      // x part: k = ks*32+quad*8 -> tap n = ks>>1, ch c0 = (ks&1)*32+quad*8
      int n = ks >> 1;
      int rowidx = (n / 3) * 18 + mrow + (n % 3);
      int lin = rowidx * 128 + (ks & 1) * 64 + quad * 16;
      bfr = *reinterpret_cast<const short8*>(winx + (lin ^ ((rowidx & 7) << 4)));
    } else {
      // po part: tap n = ks-18, ch c0 = quad*8 (of 32)
      int n = ks - 18;
      int rowidx = (n / 3) * 18 + mrow + (n % 3);
      int lin = rowidx * 64 + quad * 16;
      bfr = *reinterpret_cast<const short8*>(winp + (lin ^ ((rowidx & 3) << 4)));
    }
    acc = __builtin_amdgcn_mfma_f32_16x16x32_bf16(a, bfr, acc, 0, 0, 0);
  }

  int sp = h * Wd + w0 + mrow;
  #pragma unroll
  for (int r = 0; r < 4; ++r) {
    int gr = cotile + quad * 4 + r;
    float v = acc[r];
    if (gr < 18) {
      u_out[(b*MHc + gr)*HW + sp] = sigm(v + upd_b[gr]);
    } else if (gr < 36) {
      int oc = gr - 18;
      float rr = sigm(v + rst_b[oc]);
      roL[mrow][oc] = f2bf(rr * po[(b*MHc + oc)*HW + sp]);
    } else if (gr < 54) {
      int oc = gr - 36;
      cx_out[(b*MHc + oc)*HW + sp] = v + out_b[oc];
    } else if (gr < 63) {
      int nn = gr - 54;
      m_t[(b*HW + sp)*9 + nn] = f2bf(sigm(v + wg_b[nn]));
    }
  }
  __syncthreads();
  // coalesced ropad store: 16px x 32ch bf16 = 256 dwords, contiguous
  unsigned int* dst = (unsigned int*)(ropad + b*PPE + ((h+1)*WP + (w0+1))*32);
  dst[t] = ((unsigned int*)roL)[t];
}

// ---------------------------------------------------------------------------
// K3: fused stage-2 GEMM + offset/mean + deformable gather + warp GEMM.
// NEW: ro staged as raw window (vector loads, swizzled); gather vectorized —
// per (px,tap) the two y-corners are adjacent 64-ch blocks, so 4x short8
// loads (16B/lane) replace 4x scalar bf16 loads, with clip folded into the
// precomputed weights.
// ---------------------------------------------------------------------------
__global__ __launch_bounds__(256)
void k_fuse(const __hip_bfloat16* __restrict__ xpad,
            const __hip_bfloat16* __restrict__ ropad,
            const __hip_bfloat16* __restrict__ w2,
            const __hip_bfloat16* __restrict__ wt,
            const __hip_bfloat16* __restrict__ m_t,
            const float* __restrict__ po,
            const float* __restrict__ mean,
            float* __restrict__ out_off,    // also cx_out (read then overwrite)
            float* __restrict__ out_mn,     // also u_out  (read then overwrite)
            float* __restrict__ out_x) {
  __shared__ __align__(16) char lbuf[16*584*2];   // union: ro-window / xw
  __shared__ float offL[16][18];
  __shared__ float mL[16][9];
  __shared__ __align__(16) float gw[144][4];      // {wL0,wL1,wR0,wR1}*m
  __shared__ __align__(16) int   gb[144][2];      // {rowL base, rowR base}
  auto xw = (__hip_bfloat16(*)[584])lbuf;         // [16][584]

  int blk = blockIdx.x;
  int wtile = blk & 7;
  int h = (blk >> 3) & 127;
  int b = blk >> 10;
  int w0 = wtile * 16;
  int lane = threadIdx.x & 63;
  int wave = threadIdx.x >> 6;
  int t = threadIdx.x;

  // ---- phase 1: stage ro window [3][18][32] = 216 x 16B chunks (swizzled)
  const __hip_bfloat16* rpb = ropad + b * PPE;
  if (t < 216) {
    int r = t / 72, cidx = t - r * 72;
    short8 v = *reinterpret_cast<const short8*>(
        rpb + ((h + r) * WP + w0) * 32 + cidx * 8);
    int o = t * 16;
    *reinterpret_cast<short8*>(lbuf + (o ^ (((o >> 6) & 3) << 4))) = v;
  }
  __syncthreads();

  int mrow = lane & 15;
  int quad = lane >> 4;

  // ---- phase 2: waves 0-1 do GEMM2 + offset/mean; waves 2-3 load m ----
  if (wave < 2) {
    float4v acc = {0.f, 0.f, 0.f, 0.f};
    #pragma unroll
    for (int ks = 0; ks < KP/32; ++ks) {
      short8 a = *reinterpret_cast<const short8*>(
          w2 + (wave*16 + mrow) * KP + ks * 32 + quad * 8);
      int rowidx = (ks / 3) * 18 + mrow + (ks % 3);
      int lin = rowidx * 64 + quad * 16;
      short8 bfr = *reinterpret_cast<const short8*>(
          lbuf + (lin ^ ((rowidx & 3) << 4)));
      acc = __builtin_amdgcn_mfma_f32_16x16x32_bf16(a, bfr, acc, 0, 0, 0);
    }
    int sp = h * Wd + w0 + mrow;
    #pragma unroll
    for (int r = 0; r < 4; ++r) {
      int gr = wave*16 + quad * 4 + r;
      if (gr < 18) {
        int gi = (b*MHc + gr)*HW + sp;
        float cand = tanhf(out_off[gi] + acc[r]);   // cx (aliased)
        float u = out_mn[gi];                       // u  (aliased)
        float p = po[gi];
        float mn = 0.5f * (mean[gi] + p);
        float off = p * (1.f - u) + cand * u + mn;
        out_off[gi] = off;
        out_mn[gi]  = mn;
        offL[mrow][gr] = off;
      }
    }
  } else {
    int base = (wave - 2) * 64 + lane;
    #pragma unroll
    for (int rep = 0; rep < 2; ++rep) {
      int id = base + rep * 128;
      if (id < 144) {
        int px = id / 9, n = id % 9;
        mL[px][n] = bf2f(m_t[(b*HW + h*Wd + w0 + px)*9 + n]);
      }
    }
  }
  __syncthreads();

  // ---- phase 3: bilinear weights/bases. iyr ∈ {iyl, iyl+1} always, so the
  // two y-corners live in one 128-ch contiguous block; fold clip into weights.
  if (t < 144) {
    int px = t / 9;
    int n = t - px * 9;
    int wp = w0 + px;
    float ox = offL[px][n];
    float oy = offL[px][9 + n];
    float mnv = mL[px][n];
    float px_ = (float)(h + 1) + (float)(n / 3 - 1) + ox;
    float py_ = (float)(wp + 1) + (float)(n % 3 - 1) + oy;
    float fx = floorf(px_), fy = floorf(py_);
    float xlt = fminf(fmaxf(fx,       0.f), 129.f);
    float ylt = fminf(fmaxf(fy,       0.f), 129.f);
    float xrb = fminf(fmaxf(fx + 1.f, 0.f), 129.f);
    float yrb = fminf(fmaxf(fy + 1.f, 0.f), 129.f);
    float pxc = fminf(fmaxf(px_, 0.f), 129.f);
    float pyc = fminf(fmaxf(py_, 0.f), 129.f);
    float glt = (1.f + xlt - pxc) * (1.f + ylt - pyc);
    float grb = (1.f - xrb + pxc) * (1.f - yrb + pyc);
    float glb = (1.f + xlt - pxc) * (1.f - yrb + pyc);
    float grt = (1.f - xrb + pxc) * (1.f + ylt - pyc);
    int ixl = (int)xlt, iyl = (int)ylt, ixr = (int)xrb, iyr = (int)yrb;
    bool yAdj = (iyr == iyl + 1);       // else iyr == iyl (clipped)
    gw[t][0] = (glt + (yAdj ? 0.f : glb)) * mnv;   // row ixl, col iyl
    gw[t][1] = (yAdj ? glb : 0.f) * mnv;           // row ixl, col iyl+1
    gw[t][2] = (grt + (yAdj ? 0.f : grb)) * mnv;   // row ixr, col iyl
    gw[t][3] = (yAdj ? grb : 0.f) * mnv;           // row ixr, col iyl+1
    gb[t][0] = (ixl * WP + iyl) * Cc;
    gb[t][1] = (ixr * WP + iyl) * Cc;
  }
  __syncthreads();

  // ---- phase 4: vectorized gather. 1152 tasks = 144 (px,n) x 8 ch-octets.
  // 4x short8 (16B) loads per task; the +64 block at iyl==129 is weighted 0
  // and lands in the adjacent (finite bf16) ws region — safe.
  const __hip_bfloat16* xpb = xpad + b * XPE;
  for (int it = t; it < 1152; it += 256) {
    int q  = it >> 3;
    int c0 = (it & 7) * 8;
    float4v g = *reinterpret_cast<const float4v*>(gw[q]);
    int bL = gb[q][0], bR = gb[q][1];
    short8 l0 = *reinterpret_cast<const short8*>(xpb + bL + c0);
    short8 l1 = *reinterpret_cast<const short8*>(xpb + bL + 64 + c0);
    short8 r0 = *reinterpret_cast<const short8*>(xpb + bR + c0);
    short8 r1 = *reinterpret_cast<const short8*>(xpb + bR + 64 + c0);
    short8 ov;
    #pragma unroll
    for (int j = 0; j < 8; ++j) {
      float vv = g.x * s2f(l0[j]);
      vv = fmaf(g.y, s2f(l1[j]), vv);
      vv = fmaf(g.z, s2f(r0[j]), vv);
      vv = fmaf(g.w, s2f(r1[j]), vv);
      ov[j] = f2bs(vv);
    }
    int pl = q / 9;
    int n  = q - pl * 9;
    *reinterpret_cast<short8*>(&xw[pl][n * 64 + c0]) = ov;
  }
  __syncthreads();

  // ---- phase 5: warp GEMM 64x576 ----
  int cotile = wave * 16;
  float4v acc = {0.f, 0.f, 0.f, 0.f};
  for (int ks = 0; ks < 18; ++ks) {
    short8 a = *reinterpret_cast<const short8*>(
        wt + (cotile + mrow) * 576 + ks * 32 + quad * 8);
    short8 bfr = *reinterpret_cast<const short8*>(
        &xw[mrow][ks * 32 + quad * 8]);
    acc = __builtin_amdgcn_mfma_f32_16x16x32_bf16(a, bfr, acc, 0, 0, 0);
  }
  #pragma unroll
  for (int r = 0; r < 4; ++r) {
    int co = cotile + quad * 4 + r;
    out_x[((b * Cc + co) * Hh + h) * Wd + w0 + mrow] = acc[r];
  }
}

// ---------------------------------------------------------------------------
// Fallback (R9-verified scalar pipeline; zero ws)
// ---------------------------------------------------------------------------
__global__ void f_convAB(const float* __restrict__ x, const float* __restrict__ po,
                         const float* __restrict__ wA, const float* __restrict__ bA,
                         const float* __restrict__ wB, const float* __restrict__ bB,
                         float* __restrict__ u_scr, float* __restrict__ ro_scr) {
  int idx = blockIdx.x * 256 + threadIdx.x;
  if (idx >= Bn * MHc * HW) return;
  int w = idx & 127, h = (idx >> 7) & 127, oc = (idx >> 14) % MHc, b = idx / (MHc*HW);
  float accA = bA[oc], accB = bB[oc];
  const float* xb = x + b*Cc*HW; const float* pb = po + b*MHc*HW;
  for (int ic = 0; ic < Cc + MHc; ++ic) {
    const float* src = (ic < Cc) ? (xb + ic*HW) : (pb + (ic-Cc)*HW);
    const float* wa = wA + (oc*(Cc+MHc)+ic)*9; const float* wb = wB + (oc*(Cc+MHc)+ic)*9;
    for (int kh = 0; kh < 3; ++kh) { int hh = h+kh-1; if ((unsigned)hh >= Hh) continue;
      for (int kw = 0; kw < 3; ++kw) { int ww = w+kw-1; if ((unsigned)ww >= Wd) continue;
        float v = src[hh*Wd+ww]; accA += v*wa[kh*3+kw]; accB += v*wb[kh*3+kw]; } }
  }
  u_scr[idx] = sigm(accA); ro_scr[idx] = sigm(accB) * pb[oc*HW + h*Wd + w];
}
__global__ void f_convC(const float* __restrict__ x, const float* __restrict__ po,
                        const float* __restrict__ mean, const float* __restrict__ wC,
                        const float* __restrict__ bC, const float* __restrict__ u_scr,
                        const float* __restrict__ ro_scr, float* __restrict__ out_off,
                        float* __restrict__ out_mean) {
  int idx = blockIdx.x * 256 + threadIdx.x;
  if (idx >= Bn * MHc * HW) return;
  int w = idx & 127, h = (idx >> 7) & 127, oc = (idx >> 14) % MHc, b = idx / (MHc*HW);
  float acc = bC[oc];
  const float* xb = x + b*Cc*HW; const float* rb = ro_scr + b*MHc*HW;
  for (int ic = 0; ic < Cc + MHc; ++ic) {
    const float* src = (ic < Cc) ? (xb + ic*HW) : (rb + (ic-Cc)*HW);
    const float* wv = wC + (oc*(Cc+MHc)+ic)*9;
    for (int kh = 0; kh < 3; ++kh) { int hh = h+kh-1; if ((unsigned)hh >= Hh) continue;
      for (int kw = 0; kw < 3; ++kw) { int ww = w+kw-1; if ((unsigned)ww >= Wd) continue;
        acc += src[hh*Wd+ww]*wv[kh*3+kw]; } }
  }
  float cand = tanhf(acc); float u = u_scr[idx]; float p = po[idx];
  float mn = 0.5f*(mean[idx]+p);
  out_off[idx] = p*(1.f-u)+cand*u+mn; out_mean[idx] = mn;
}
__global__ __launch_bounds__(256)
void f_warp(const float* __restrict__ x, const float* __restrict__ off_f,
            const float* __restrict__ wg, const float* __restrict__ bg,
            const float* __restrict__ wc, float* __restrict__ out) {
  __shared__ float mred[4][Np][64]; __shared__ float mval[4][Np];
  __shared__ float xwv[4][Np][64];
  int lane = threadIdx.x & 63, wave = threadIdx.x >> 6;
  int p = blockIdx.x * 4 + wave;
  int b = p >> 14, rem = p & 16383, h = rem >> 7, w = rem & 127;
  const float* xc = x + (b*Cc + lane)*HW;
  float part[Np];
  for (int n = 0; n < Np; ++n) part[n] = 0.f;
  for (int kh = 0; kh < 3; ++kh) { int hh = h+kh-1; if ((unsigned)hh >= Hh) continue;
    for (int kw = 0; kw < 3; ++kw) { int ww = w+kw-1; if ((unsigned)ww >= Wd) continue;
      float v = xc[hh*Wd+ww];
      for (int n = 0; n < Np; ++n) part[n] += v*wg[(n*Cc+lane)*9+kh*3+kw]; } }
  for (int n = 0; n < Np; ++n) mred[wave][n][lane] = part[n];
  __syncthreads();
  if (lane < Np) { float s = bg[lane];
    for (int c = 0; c < Cc; ++c) s += mred[wave][lane][c];
    mval[wave][lane] = sigm(s); }
  __syncthreads();
  const float* offb = off_f + b*MHc*HW; int sp = h*Wd + w;
  for (int n = 0; n < Np; ++n) {
    float px = (float)(h+1) + (float)(n/3-1) + offb[n*HW+sp];
    float py = (float)(w+1) + (float)(n%3-1) + offb[(9+n)*HW+sp];
    float fxq = floorf(px), fyq = floorf(py);
    float xlt = fminf(fmaxf(fxq,0.f),129.f), ylt = fminf(fmaxf(fyq,0.f),129.f);
    float xrb = fminf(fmaxf(fxq+1.f,0.f),129.f), yrb = fminf(fmaxf(fyq+1.f,0.f),129.f);
    float pxc = fminf(fmaxf(px,0.f),129.f), pyc = fminf(fmaxf(py,0.f),129.f);
    float glt = (1.f+xlt-pxc)*(1.f+ylt-pyc), grb = (1.f-xrb+pxc)*(1.f-yrb+pyc);
    float glb = (1.f+xlt-pxc)*(1.f-yrb+pyc), grt = (1.f-xrb+pxc)*(1.f+ylt-pyc);
    int ixl=(int)xlt, iyl=(int)ylt, ixr=(int)xrb, iyr=(int)yrb;
    float vlt=0.f,vrb=0.f,vlb=0.f,vrt=0.f;
    if (ixl>=1&&ixl<=Hh&&iyl>=1&&iyl<=Wd) vlt = xc[(ixl-1)*Wd+(iyl-1)];
    if (ixr>=1&&ixr<=Hh&&iyr>=1&&iyr<=Wd) vrb = xc[(ixr-1)*Wd+(iyr-1)];
    if (ixl>=1&&ixl<=Hh&&iyr>=1&&iyr<=Wd) vlb = xc[(ixl-1)*Wd+(iyr-1)];
    if (ixr>=1&&ixr<=Hh&&iyl>=1&&iyl<=Wd) vrt = xc[(ixr-1)*Wd+(iyl-1)];
    xwv[wave][n][lane] = (glt*vlt+grb*vrb+glb*vlb+grt*vrt)*mval[wave][n];
  }
  __syncthreads();
  float acc = 0.f;
  for (int c = 0; c < Cc; ++c)
    for (int n = 0; n < Np; ++n)
      acc += xwv[wave][n][c]*wc[(lane*Cc+c)*9+n];
  out[(b*Cc+lane)*HW + h*Wd + w] = acc;
}

// ---------------------------------------------------------------------------
extern "C" void kernel_launch(void* const* d_in, const int* in_sizes, int n_in,
                              void* d_out, int out_size, void* d_ws, size_t ws_size,
                              hipStream_t stream) {
  (void)in_sizes; (void)n_in; (void)out_size;
  const float* x_t   = (const float*)d_in[0];
  const float* po    = (const float*)d_in[1];
  const float* mean  = (const float*)d_in[2];
  const float* upd_w = (const float*)d_in[3];
  const float* upd_b = (const float*)d_in[4];
  const float* rst_w = (const float*)d_in[5];
  const float* rst_b = (const float*)d_in[6];
  const float* out_w = (const float*)d_in[7];
  const float* out_b = (const float*)d_in[8];
  const float* wg_w  = (const float*)d_in[9];
  const float* wg_b  = (const float*)d_in[10];
  const float* wcw   = (const float*)d_in[11];

  float* out_x   = (float*)d_out;            // [4,64,128,128]
  float* out_off = out_x + 4194304;          // [4,18,128,128]
  float* out_mn  = out_off + 1179648;        // [4,18,128,128]

  char* ws = (char*)d_ws;
  __hip_bfloat16* xpad  = (__hip_bfloat16*)(ws + 0);          //  8,652,800
  __hip_bfloat16* popad = (__hip_bfloat16*)(ws + 8652800);    //  4,326,400
  __hip_bfloat16* ropad = (__hip_bfloat16*)(ws + 12979200);   //  4,326,400
  __hip_bfloat16* wall  = (__hip_bfloat16*)(ws + 17305600);   //    110,592
  __hip_bfloat16* w2    = (__hip_bfloat16*)(ws + 17416192);   //     18,432
  __hip_bfloat16* wt_bf = (__hip_bfloat16*)(ws + 17434624);   //     73,728
  __hip_bfloat16* m_t   = (__hip_bfloat16*)(ws + 17508352);   //  1,179,648
  const size_t WS_NEED = 18688000;

  if (ws_size >= WS_NEED) {
    hipMemsetAsync(d_ws, 0, 17305600, stream);   // xpad+popad+ropad borders
    hipLaunchKernelGGL(k_prep,  dim3(5004), dim3(256), 0, stream,
                       x_t, po, upd_w, rst_w, out_w, wg_w, wcw,
                       xpad, popad, wall, w2, wt_bf);
    // u -> out_mn region, cx -> out_off region (exact [B,18,HW] aliases;
    // k_fuse reads each address before overwriting it)
    hipLaunchKernelGGL(k_gates, dim3(4096), dim3(256), 0, stream,
                       xpad, popad, wall, po, upd_b, rst_b, out_b, wg_b,
                       out_mn, out_off, ropad, m_t);
    hipLaunchKernelGGL(k_fuse,  dim3(4096), dim3(256), 0, stream,
                       xpad, ropad, w2, wt_bf, m_t, po, mean,
                       out_off, out_mn, out_x);
  } else {
    float* u_scr  = out_x;
    float* cx_scr = out_x + 1179648;
    hipLaunchKernelGGL(f_convAB, dim3(4608), dim3(256), 0, stream,
                       x_t, po, upd_w, upd_b, rst_w, rst_b, u_scr, cx_scr);
    hipLaunchKernelGGL(f_convC,  dim3(4608), dim3(256), 0, stream,
                       x_t, po, mean, out_w, out_b, u_scr, cx_scr,
                       out_off, out_mn);
    hipLaunchKernelGGL(f_warp,   dim3(16384), dim3(256), 0, stream,
                       x_t, out_off, wg_w, wg_b, wcw, out_x);
  }
}